// Round 23
// baseline (371.490 us; speedup 1.0000x reference)
//
#include <hip/hip_runtime.h>
#include <stdint.h>

#define NPOS 262144       // 512*512
#define EPS_LN 1e-5f
#define ZSTRIDE 272       // 128 f16 + 16B pad (breaks power-of-2 bank stride)

typedef _Float16 f16x8_t __attribute__((ext_vector_type(8)));
typedef float f32x4_t __attribute__((ext_vector_type(4)));

static __device__ __forceinline__ unsigned short f2h(float f) {
    union { _Float16 h; unsigned short u; } v;
    v.h = (_Float16)f;
    return v.u;
}
static __device__ __forceinline__ float h2f(unsigned short u) {
    union { unsigned short u; _Float16 h; } v;
    v.u = u;
    return (float)v.h;
}
static __device__ __forceinline__ float sigmoidf_(float x) {
    return 1.0f / (1.0f + __expf(-x));
}

#define GLOAD_LDS16(gp, lp) __builtin_amdgcn_global_load_lds( \
    (const __attribute__((address_space(1))) void*)(gp), \
    (__attribute__((address_space(3))) void*)(lp), 16, 0, 0)

// ---------------------------------------------------------------------------
// k_prep6: transpose+cast+FOLD 6 weight matrices -> f16 h-major planes.
// plane order: 0:ap 1:ag 2:bp 3:bg 4:z 5:g.
// Planes 0-3,5 folded with ln_in_g; plane 4 folded with ln_out_g.
// ---------------------------------------------------------------------------
__global__ __launch_bounds__(256)
void k_prep6(const float* w0, const float* w1, const float* w2,
             const float* w3, const float* w4, const float* w5,
             const float* lng, const float* lnog, unsigned short* wt) {
    const float* srcs[6] = {w0, w1, w2, w3, w4, w5};
    const float* src = srcs[blockIdx.x];
    const float* fold = (blockIdx.x == 4) ? lnog : lng;
    unsigned short* dst = wt + blockIdx.x * 16384;
    for (int rep = 0; rep < 64; ++rep) {
        int idx = rep * 256 + threadIdx.x;   // 0..16383
        int h = idx >> 7, k = idx & 127;
        dst[idx] = f2h(src[k * 128 + h] * fold[k]);
    }
}

// ---------------------------------------------------------------------------
// k_const: per matrix: C1[c]=sum_k gv[k]*W[k][c], C2[c]=sum_k bv[k]*W[k][c]
// cc layout: [6][2][128]
// ---------------------------------------------------------------------------
__global__ __launch_bounds__(128)
void k_const(const float* wap, const float* wag, const float* wbp,
             const float* wbg, const float* wz, const float* wg,
             const float* lng, const float* lnb,
             const float* lnog, const float* lnob, float* cc) {
    const float* Ws[6] = {wap, wag, wbp, wbg, wz, wg};
    const float* W = Ws[blockIdx.x];
    const float* gv = (blockIdx.x == 4) ? lnog : lng;
    const float* bv = (blockIdx.x == 4) ? lnob : lnb;
    int c = threadIdx.x;
    float s1 = 0.f, s2 = 0.f;
    for (int k = 0; k < 128; ++k) {
        float wv = W[k * 128 + c];
        s1 += gv[k] * wv;
        s2 += bv[k] * wv;
    }
    cc[blockIdx.x * 256 + c] = s1;
    cc[blockIdx.x * 256 + 128 + c] = s2;
}

// ---------------------------------------------------------------------------
// k_zcvt (NEW): stream z f32 -> z16 f16 plane + packed f16 (mu,rstd) per row.
// 4 threads/row, 64 rows/block, grid 4096. No LDS, no barrier.
// Stats computed from RAW f32 (matches reference LN).
// ---------------------------------------------------------------------------
__global__ __launch_bounds__(256)
void k_zcvt(const float* __restrict__ z, unsigned short* __restrict__ z16,
            unsigned* __restrict__ mustd) {
    const int t = threadIdx.x;
    const int row = blockIdx.x * 64 + (t >> 2);
    const int q = t & 3;
    const float* zp = z + (size_t)row * 128 + q * 32;
    float s = 0.f, s2 = 0.f;
    #pragma unroll
    for (int e = 0; e < 8; ++e) {
        float4 v = *(const float4*)(zp + e * 4);
        s += v.x + v.y + v.z + v.w;
        s2 += v.x * v.x + v.y * v.y + v.z * v.z + v.w * v.w;
        uint2 st;
        st.x = f2h(v.x) | ((unsigned)f2h(v.y) << 16);
        st.y = f2h(v.z) | ((unsigned)f2h(v.w) << 16);
        *(uint2*)(z16 + (size_t)row * 128 + q * 32 + e * 4) = st;
    }
    s  += __shfl_xor(s, 1);  s  += __shfl_xor(s, 2);
    s2 += __shfl_xor(s2, 1); s2 += __shfl_xor(s2, 2);
    float mu = s * (1.0f / 128.0f);
    float var = s2 * (1.0f / 128.0f) - mu * mu;
    float rstd = rsqrtf(var + EPS_LN);
    if (q == 0) mustd[row] = f2h(mu) | ((unsigned)f2h(rstd) << 16);
}

// ---------------------------------------------------------------------------
// k1f (NEW): LN-folded a/b projections, NO LDS, NO BARRIER.
// A-fragments read DIRECTLY from global z16 (64B-coalesced per wave, L2-hot);
// B-fragments from folded wt planes; affine via cc + mustd; mask in epilogue.
// 512 threads (8 waves, fully independent), 128 positions/block, grid 2048.
// ---------------------------------------------------------------------------
__global__ __launch_bounds__(512, 2)
void k1f(const unsigned short* __restrict__ z16,
         const unsigned* __restrict__ mustd,
         const float* __restrict__ mask,
         const unsigned short* __restrict__ wt, const float* __restrict__ cc,
         const float* __restrict__ b_ap, const float* __restrict__ b_ag,
         const float* __restrict__ b_bp, const float* __restrict__ b_bg,
         unsigned short* __restrict__ a_t, unsigned short* __restrict__ b_t)
{
    const int t = threadIdx.x;
    const int lane = t & 63;
    const int w = t >> 6;                // wave 0..7
    const int g = lane >> 4;             // k-subgroup 0..3
    const int l15 = lane & 15;
    const int h = w * 16 + l15;          // this wave's output column
    const int p0 = blockIdx.x * 128;

    // ---- weight B-fragments (folded planes): 16 vector loads ----
    f16x8_t wapf[4], wagf[4], wbpf[4], wbgf[4];
    #pragma unroll
    for (int kk = 0; kk < 4; ++kk) {
        int off = h * 128 + kk * 32 + g * 8;
        wapf[kk] = *(const f16x8_t*)(wt + 0 * 16384 + off);
        wagf[kk] = *(const f16x8_t*)(wt + 1 * 16384 + off);
        wbpf[kk] = *(const f16x8_t*)(wt + 2 * 16384 + off);
        wbgf[kk] = *(const f16x8_t*)(wt + 3 * 16384 + off);
    }
    const float C1ap = cc[0 * 256 + h], C2ap = cc[0 * 256 + 128 + h];
    const float C1ag = cc[1 * 256 + h], C2ag = cc[1 * 256 + 128 + h];
    const float C1bp = cc[2 * 256 + h], C2bp = cc[2 * 256 + 128 + h];
    const float C1bg = cc[3 * 256 + h], C2bg = cc[3 * 256 + 128 + h];
    const float bap = b_ap[h], bag = b_ag[h];
    const float bbp = b_bp[h], bbg = b_bg[h];

    f32x4_t zero = {0.f, 0.f, 0.f, 0.f};
    #pragma unroll 1
    for (int rt = 0; rt < 8; ++rt) {
        const int row = p0 + rt * 16 + l15;
        f32x4_t accAP = zero, accAG = zero, accBP = zero, accBG = zero;
        #pragma unroll
        for (int kk = 0; kk < 4; ++kk) {
            f16x8_t ax = *(const f16x8_t*)(z16 + (size_t)row * 128 + kk * 32 + g * 8);
            accAP = __builtin_amdgcn_mfma_f32_16x16x32_f16(ax, wapf[kk], accAP, 0, 0, 0);
            accAG = __builtin_amdgcn_mfma_f32_16x16x32_f16(ax, wagf[kk], accAG, 0, 0, 0);
            accBP = __builtin_amdgcn_mfma_f32_16x16x32_f16(ax, wbpf[kk], accBP, 0, 0, 0);
            accBG = __builtin_amdgcn_mfma_f32_16x16x32_f16(ax, wbgf[kk], accBG, 0, 0, 0);
        }
        int pb = p0 + rt * 16 + g * 4;
        unsigned short pka[4], pkb[4];
        #pragma unroll
        for (int r = 0; r < 4; ++r) {
            unsigned msv = mustd[pb + r];
            float mu = h2f((unsigned short)(msv & 0xffffu));
            float rstd = h2f((unsigned short)(msv >> 16));
            float vAP = rstd * (accAP[r] - mu * C1ap) + C2ap + bap;
            float vAG = rstd * (accAG[r] - mu * C1ag) + C2ag + bag;
            float vBP = rstd * (accBP[r] - mu * C1bp) + C2bp + bbp;
            float vBG = rstd * (accBG[r] - mu * C1bg) + C2bg + bbg;
            float m = mask[pb + r];
            pka[r] = f2h(m * sigmoidf_(vAG) * vAP);
            pkb[r] = f2h(m * sigmoidf_(vBG) * vBP);
        }
        uint2 sta, stb;
        sta.x = pka[0] | ((unsigned)pka[1] << 16);
        sta.y = pka[2] | ((unsigned)pka[3] << 16);
        stb.x = pkb[0] | ((unsigned)pkb[1] << 16);
        stb.y = pkb[2] | ((unsigned)pkb[3] << 16);
        *(uint2*)(a_t + (size_t)h * NPOS + pb) = sta;
        *(uint2*)(b_t + (size_t)h * NPOS + pb) = stb;
    }
}

// ---------------------------------------------------------------------------
// k2 (VALIDATED R7): per-h triangle GEMM
//   x_t[h][i][k] = sum_j a_t[h][i][j] * b_t[h][k][j]
// ---------------------------------------------------------------------------
__global__ __launch_bounds__(256, 2)
void k2_tri(const unsigned short* __restrict__ a_t,
            const unsigned short* __restrict__ b_t,
            unsigned short* __restrict__ x_t) {
    __shared__ char sA[16384];   // [128][64] f16 linear
    __shared__ char sB[16384];
    const int t = threadIdx.x;
    const int lane = t & 63;
    const int w = t >> 6;
    const int wr = w >> 1, wc = w & 1;
    const int h = blockIdx.y;
    const int i0 = (blockIdx.x >> 2) * 128;
    const int k0 = (blockIdx.x & 3) * 128;
    const unsigned short* Abase = a_t + (size_t)h * NPOS;
    const unsigned short* Bbase = b_t + (size_t)h * NPOS;

    f32x4_t zero = {0.f, 0.f, 0.f, 0.f};
    f32x4_t acc[4][4];
    #pragma unroll
    for (int m = 0; m < 4; ++m)
        #pragma unroll
        for (int n = 0; n < 4; ++n) acc[m][n] = zero;

    for (int kt = 0; kt < 8; ++kt) {
        #pragma unroll
        for (int pass = 0; pass < 4; ++pass) {
            int ci = pass * 256 + t;
            int row = ci >> 3, ch = ci & 7;
            const unsigned short* gA = Abase + (size_t)(i0 + row) * 512 + kt * 64 + ch * 8;
            const unsigned short* gB = Bbase + (size_t)(k0 + row) * 512 + kt * 64 + ch * 8;
            GLOAD_LDS16(gA, sA + w * 1024 + pass * 4096);
            GLOAD_LDS16(gB, sB + w * 1024 + pass * 4096);
        }
        __syncthreads();
        #pragma unroll
        for (int ks = 0; ks < 2; ++ks) {
            f16x8_t af[4], bf[4];
            #pragma unroll
            for (int m = 0; m < 4; ++m) {
                int ar = wr * 64 + m * 16 + (lane & 15);
                af[m] = *(const f16x8_t*)(sA + ar * 128 + ks * 64 + (lane >> 4) * 16);
            }
            #pragma unroll
            for (int n = 0; n < 4; ++n) {
                int br = wc * 64 + n * 16 + (lane & 15);
                bf[n] = *(const f16x8_t*)(sB + br * 128 + ks * 64 + (lane >> 4) * 16);
            }
            #pragma unroll
            for (int m = 0; m < 4; ++m)
                #pragma unroll
                for (int n = 0; n < 4; ++n)
                    acc[m][n] = __builtin_amdgcn_mfma_f32_16x16x32_f16(af[m], bf[n], acc[m][n], 0, 0, 0);
        }
        __syncthreads();
    }
    #pragma unroll
    for (int m = 0; m < 4; ++m) {
        int i = i0 + wr * 64 + m * 16 + (lane >> 4) * 4;
        #pragma unroll
        for (int n = 0; n < 4; ++n) {
            int k = k0 + wc * 64 + n * 16 + (lane & 15);
            #pragma unroll
            for (int r = 0; r < 4; ++r) {
                x_t[(size_t)h * NPOS + (size_t)(i + r) * 512 + k] = f2h(acc[m][n][r]);
            }
        }
    }
}

// ---------------------------------------------------------------------------
// k3d (VALIDATED R21/R22): double LN-FOLDED output stage.
//   out = ( rstdX*(accX - muX*C1z) + C2z + bz ) *
//         sigmoid( rstdZ*(accG - muZ*C1g) + C2g + bg )
// ---------------------------------------------------------------------------
__global__ __launch_bounds__(512, 2)
void k3d(const unsigned short* __restrict__ x_t,
         const unsigned short* __restrict__ z16,
         const unsigned* __restrict__ mustd,
         const unsigned short* __restrict__ wt, const float* __restrict__ cc,
         const float* __restrict__ b_z, const float* __restrict__ b_g,
         float* __restrict__ out)
{
    __shared__ char sX[128 * ZSTRIDE];   // [128 pos][128 h] f16, padded rows
    __shared__ float smuX[128], srstdX[128];
    __shared__ float smuZ[128], srstdZ[128];
    const int t = threadIdx.x, lane = t & 63, w = t >> 6;
    const int g = lane >> 4;             // k-subgroup 0..3
    const int c = w * 16 + (lane & 15);  // this wave's output column
    const int p0 = blockIdx.x * 128;

    // ---- weight fragments (folded planes) ----
    f16x8_t wzf[4], wgf[4];
    #pragma unroll
    for (int kk = 0; kk < 4; ++kk) {
        int off = c * 128 + kk * 32 + g * 8;
        wzf[kk] = *(const f16x8_t*)(wt + 4 * 16384 + off);
        wgf[kk] = *(const f16x8_t*)(wt + 5 * 16384 + off);
    }
    const float bzv = b_z[c], bgv = b_g[c];
    const float C1z = cc[4 * 256 + c], C2z = cc[4 * 256 + 128 + c];
    const float C1g = cc[5 * 256 + c], C2g = cc[5 * 256 + 128 + c];

    // ---- z stats for this block's 128 rows ----
    if (t < 128) {
        unsigned v = mustd[p0 + t];
        smuZ[t] = h2f((unsigned short)(v & 0xffffu));
        srstdZ[t] = h2f((unsigned short)(v >> 16));
    }

    // ---- stage x transposed: lane = h-pair, wave = 16-p segment ----
    {
        const int hp = lane;
        const int ps = w * 16;
        const unsigned short* x0 = x_t + (size_t)(2 * hp) * NPOS + p0 + ps;
        const unsigned short* x1 = x_t + (size_t)(2 * hp + 1) * NPOS + p0 + ps;
        uint4 a0 = *(const uint4*)(x0);
        uint4 a1 = *(const uint4*)(x0 + 8);
        uint4 b0 = *(const uint4*)(x1);
        uint4 b1 = *(const uint4*)(x1 + 8);
        unsigned aw[8] = {a0.x, a0.y, a0.z, a0.w, a1.x, a1.y, a1.z, a1.w};
        unsigned bw[8] = {b0.x, b0.y, b0.z, b0.w, b1.x, b1.y, b1.z, b1.w};
        #pragma unroll
        for (int e = 0; e < 8; ++e) {
            int p = ps + 2 * e;
            *(unsigned*)(sX + p * ZSTRIDE + hp * 4) =
                (aw[e] & 0xffffu) | ((bw[e] & 0xffffu) << 16);
            *(unsigned*)(sX + (p + 1) * ZSTRIDE + hp * 4) =
                (aw[e] >> 16) | ((bw[e] >> 16) << 16);
        }
    }
    __syncthreads();
    // ---- x LN stats only (4 threads per position) ----
    {
        int pos = t >> 2, q = t & 3;
        float s = 0.f, s2 = 0.f;
        #pragma unroll
        for (int e = 0; e < 8; ++e) {
            uint2 vv = *(const uint2*)(sX + pos * ZSTRIDE + (q * 32 + e * 4) * 2);
            float v0 = h2f((unsigned short)(vv.x & 0xffffu));
            float v1 = h2f((unsigned short)(vv.x >> 16));
            float v2 = h2f((unsigned short)(vv.y & 0xffffu));
            float v3 = h2f((unsigned short)(vv.y >> 16));
            s  += v0 + v1 + v2 + v3;
            s2 += v0 * v0 + v1 * v1 + v2 * v2 + v3 * v3;
        }
        s  += __shfl_xor(s, 1);  s  += __shfl_xor(s, 2);
        s2 += __shfl_xor(s2, 1); s2 += __shfl_xor(s2, 2);
        float mu = s * (1.0f / 128.0f);
        float var = s2 * (1.0f / 128.0f) - mu * mu;
        if (q == 0) {
            smuX[pos] = mu;
            srstdX[pos] = rsqrtf(var + EPS_LN);
        }
    }
    __syncthreads();
    // ---- MFMA row tiles ----
    f32x4_t zero = {0.f, 0.f, 0.f, 0.f};
    for (int rt = 0; rt < 8; ++rt) {
        f32x4_t accX = zero, accG = zero;
        #pragma unroll
        for (int kk = 0; kk < 4; ++kk) {
            int row = rt * 16 + (lane & 15);
            f16x8_t ax = *(const f16x8_t*)(sX + row * ZSTRIDE + kk * 64 + g * 16);
            f16x8_t az = *(const f16x8_t*)(z16 + (size_t)(p0 + row) * 128 + kk * 32 + g * 8);
            accX = __builtin_amdgcn_mfma_f32_16x16x32_f16(ax, wzf[kk], accX, 0, 0, 0);
            accG = __builtin_amdgcn_mfma_f32_16x16x32_f16(az, wgf[kk], accG, 0, 0, 0);
        }
        int lr0 = rt * 16 + g * 4;
        #pragma unroll
        for (int r = 0; r < 4; ++r) {
            int lr = lr0 + r;
            float oz = srstdX[lr] * (accX[r] - smuX[lr] * C1z) + C2z + bzv;
            float lg = srstdZ[lr] * (accG[r] - smuZ[lr] * C1g) + C2g + bgv;
            out[(size_t)(p0 + lr) * 128 + c] = oz * sigmoidf_(lg);
        }
    }
}

extern "C" void kernel_launch(void* const* d_in, const int* in_sizes, int n_in,
                              void* d_out, int out_size, void* d_ws, size_t ws_size,
                              hipStream_t stream) {
    const float* z        = (const float*)d_in[0];
    const float* mask     = (const float*)d_in[1];
    const float* ln_in_g  = (const float*)d_in[2];
    const float* ln_in_b  = (const float*)d_in[3];
    const float* w_ap     = (const float*)d_in[4];
    const float* b_ap     = (const float*)d_in[5];
    const float* w_ag     = (const float*)d_in[6];
    const float* b_ag     = (const float*)d_in[7];
    const float* w_bp     = (const float*)d_in[8];
    const float* b_bp     = (const float*)d_in[9];
    const float* w_bg     = (const float*)d_in[10];
    const float* b_bg     = (const float*)d_in[11];
    const float* w_g      = (const float*)d_in[12];
    const float* b_g      = (const float*)d_in[13];
    const float* ln_out_g = (const float*)d_in[14];
    const float* ln_out_b = (const float*)d_in[15];
    const float* w_z      = (const float*)d_in[16];
    const float* b_z      = (const float*)d_in[17];
    float* out = (float*)d_out;

    char* ws = (char*)d_ws;
    const size_t MB64 = (size_t)NPOS * 128 * 2;   // 64 MB per f16 plane-set
    unsigned short* wt   = (unsigned short*)(ws);                 // 192 KB
    float*          cc   = (float*)(ws + 786432);                 // 6 KB
    unsigned*      mustd = (unsigned*)(ws + (1 << 20));           // 1 MB
    unsigned short* a_t  = (unsigned short*)(ws + (2 << 20));
    unsigned short* b_t  = (unsigned short*)(ws + (2 << 20) + MB64);
    unsigned short* x_t  = (unsigned short*)(ws + (2 << 20) + 2 * MB64);
    unsigned short* z16  = (unsigned short*)(ws + (2 << 20) + 3 * MB64); // 270 MB

    k_prep6<<<6, 256, 0, stream>>>(w_ap, w_ag, w_bp, w_bg, w_z, w_g,
                                   ln_in_g, ln_out_g, wt);
    k_const<<<6, 128, 0, stream>>>(w_ap, w_ag, w_bp, w_bg, w_z, w_g,
                                   ln_in_g, ln_in_b, ln_out_g, ln_out_b, cc);
    k_zcvt<<<4096, 256, 0, stream>>>(z, z16, mustd);
    k1f<<<2048, 512, 0, stream>>>(z16, mustd, mask, wt, cc,
                                  b_ap, b_ag, b_bp, b_bg, a_t, b_t);
    k2_tri<<<dim3(16, 128), 256, 0, stream>>>(a_t, b_t, x_t);
    k3d<<<2048, 512, 0, stream>>>(x_t, z16, mustd, wt, cc, b_z, b_g, out);
}

// Round 24
// 343.776 us; speedup vs baseline: 1.0806x; 1.0806x over previous
//
#include <hip/hip_runtime.h>
#include <stdint.h>

#define NPOS 262144       // 512*512
#define EPS_LN 1e-5f
#define ZSTRIDE 272       // 128 f16 + 16B pad (breaks power-of-2 bank stride)

typedef _Float16 f16x8_t __attribute__((ext_vector_type(8)));
typedef float f32x4_t __attribute__((ext_vector_type(4)));

static __device__ __forceinline__ unsigned short f2h(float f) {
    union { _Float16 h; unsigned short u; } v;
    v.h = (_Float16)f;
    return v.u;
}
static __device__ __forceinline__ float h2f(unsigned short u) {
    union { unsigned short u; _Float16 h; } v;
    v.u = u;
    return (float)v.h;
}
static __device__ __forceinline__ float sigmoidf_(float x) {
    return 1.0f / (1.0f + __expf(-x));
}

#define GLOAD_LDS16(gp, lp) __builtin_amdgcn_global_load_lds( \
    (const __attribute__((address_space(1))) void*)(gp), \
    (__attribute__((address_space(3))) void*)(lp), 16, 0, 0)

// ---------------------------------------------------------------------------
// k_prep6: transpose+cast+FOLD 6 weight matrices -> f16 h-major planes.
// plane order: 0:ap 1:ag 2:bp 3:bg 4:z 5:g.
// Planes 0-3,5 folded with ln_in_g; plane 4 folded with ln_out_g.
// ---------------------------------------------------------------------------
__global__ __launch_bounds__(256)
void k_prep6(const float* w0, const float* w1, const float* w2,
             const float* w3, const float* w4, const float* w5,
             const float* lng, const float* lnog, unsigned short* wt) {
    const float* srcs[6] = {w0, w1, w2, w3, w4, w5};
    const float* src = srcs[blockIdx.x];
    const float* fold = (blockIdx.x == 4) ? lnog : lng;
    unsigned short* dst = wt + blockIdx.x * 16384;
    for (int rep = 0; rep < 64; ++rep) {
        int idx = rep * 256 + threadIdx.x;   // 0..16383
        int h = idx >> 7, k = idx & 127;
        dst[idx] = f2h(src[k * 128 + h] * fold[k]);
    }
}

// ---------------------------------------------------------------------------
// k_const: per matrix: C1[c]=sum_k gv[k]*W[k][c], C2[c]=sum_k bv[k]*W[k][c]
// cc layout: [6][2][128]
// ---------------------------------------------------------------------------
__global__ __launch_bounds__(128)
void k_const(const float* wap, const float* wag, const float* wbp,
             const float* wbg, const float* wz, const float* wg,
             const float* lng, const float* lnb,
             const float* lnog, const float* lnob, float* cc) {
    const float* Ws[6] = {wap, wag, wbp, wbg, wz, wg};
    const float* W = Ws[blockIdx.x];
    const float* gv = (blockIdx.x == 4) ? lnog : lng;
    const float* bv = (blockIdx.x == 4) ? lnob : lnb;
    int c = threadIdx.x;
    float s1 = 0.f, s2 = 0.f;
    for (int k = 0; k < 128; ++k) {
        float wv = W[k * 128 + c];
        s1 += gv[k] * wv;
        s2 += bv[k] * wv;
    }
    cc[blockIdx.x * 256 + c] = s1;
    cc[blockIdx.x * 256 + 128 + c] = s2;
}

// ---------------------------------------------------------------------------
// k1g: LN-folded a/b projections with BLOCKED output layout.
//   a_t/b_t stored as [pblk=p>>7][h][ppos=p&127] f16  (pblk = blockIdx.x).
//   Wave-stores now land in a 4KB window (16x32B, one DRAM page) instead of
//   scattering across 16 h-planes 512KB apart (R23 diagnosis: ~1TB/s write).
// Stages own 128 rows of z f32->f16 (LDS + z16 plane + stats), then MFMA.
// 512 threads, 128 positions/block, grid 2048.
// ---------------------------------------------------------------------------
__global__ __launch_bounds__(512, 2)
void k1g(const float* __restrict__ z, const float* __restrict__ mask,
         const unsigned short* __restrict__ wt, const float* __restrict__ cc,
         const float* __restrict__ b_ap, const float* __restrict__ b_ag,
         const float* __restrict__ b_bp, const float* __restrict__ b_bg,
         unsigned short* __restrict__ a_t, unsigned short* __restrict__ b_t,
         unsigned short* __restrict__ z16, unsigned* __restrict__ mustd)
{
    __shared__ char sZ[128 * ZSTRIDE];   // [128 pos][128 ch] raw f16 z
    __shared__ float smu[128];
    __shared__ float srstd[128];
    const int t = threadIdx.x;
    const int lane = t & 63;
    const int w = t >> 6;                // wave 0..7
    const int g = lane >> 4;             // k-subgroup 0..3
    const int l15 = lane & 15;
    const int h = w * 16 + l15;          // this wave's output column
    const int p0 = blockIdx.x * 128;

    // ---- stage raw z as f16 + stats (4 threads per position; R21-validated)
    {
        const int pos = t >> 2, q = t & 3;
        const float* zp = z + (size_t)(p0 + pos) * 128 + q * 32;
        float s = 0.f, s2 = 0.f;
        #pragma unroll
        for (int e = 0; e < 8; ++e) {
            float4 v = *(const float4*)(zp + e * 4);
            s += v.x + v.y + v.z + v.w;
            s2 += v.x * v.x + v.y * v.y + v.z * v.z + v.w * v.w;
            uint2 st;
            st.x = f2h(v.x) | ((unsigned)f2h(v.y) << 16);
            st.y = f2h(v.z) | ((unsigned)f2h(v.w) << 16);
            *(uint2*)(sZ + pos * ZSTRIDE + (q * 32 + e * 4) * 2) = st;
            *(uint2*)(z16 + (size_t)(p0 + pos) * 128 + q * 32 + e * 4) = st;
        }
        s  += __shfl_xor(s, 1);  s  += __shfl_xor(s, 2);
        s2 += __shfl_xor(s2, 1); s2 += __shfl_xor(s2, 2);
        float mu = s * (1.0f / 128.0f);
        float var = s2 * (1.0f / 128.0f) - mu * mu;
        float rstd = rsqrtf(var + EPS_LN);
        if (q == 0) {
            smu[pos] = mu;
            srstd[pos] = rstd;
            mustd[p0 + pos] = f2h(mu) | ((unsigned)f2h(rstd) << 16);
        }
    }

    // ---- weight B-fragments (folded planes) + constants ----
    f16x8_t wapf[4], wagf[4], wbpf[4], wbgf[4];
    #pragma unroll
    for (int kk = 0; kk < 4; ++kk) {
        int off = h * 128 + kk * 32 + g * 8;
        wapf[kk] = *(const f16x8_t*)(wt + 0 * 16384 + off);
        wagf[kk] = *(const f16x8_t*)(wt + 1 * 16384 + off);
        wbpf[kk] = *(const f16x8_t*)(wt + 2 * 16384 + off);
        wbgf[kk] = *(const f16x8_t*)(wt + 3 * 16384 + off);
    }
    const float C1ap = cc[0 * 256 + h], C2ap = cc[0 * 256 + 128 + h];
    const float C1ag = cc[1 * 256 + h], C2ag = cc[1 * 256 + 128 + h];
    const float C1bp = cc[2 * 256 + h], C2bp = cc[2 * 256 + 128 + h];
    const float C1bg = cc[3 * 256 + h], C2bg = cc[3 * 256 + 128 + h];
    const float bap = b_ap[h], bag = b_ag[h];
    const float bbp = b_bp[h], bbg = b_bg[h];
    __syncthreads();

    // ---- MFMA row tiles + blocked-layout stores ----
    unsigned short* aBlk = a_t + (size_t)blockIdx.x * 16384 + h * 128;
    unsigned short* bBlk = b_t + (size_t)blockIdx.x * 16384 + h * 128;
    f32x4_t zero = {0.f, 0.f, 0.f, 0.f};
    for (int rt = 0; rt < 8; ++rt) {
        f32x4_t accAP = zero, accAG = zero, accBP = zero, accBG = zero;
        #pragma unroll
        for (int kk = 0; kk < 4; ++kk) {
            f16x8_t ax = *(const f16x8_t*)(sZ + (rt * 16 + l15) * ZSTRIDE + kk * 64 + g * 16);
            accAP = __builtin_amdgcn_mfma_f32_16x16x32_f16(ax, wapf[kk], accAP, 0, 0, 0);
            accAG = __builtin_amdgcn_mfma_f32_16x16x32_f16(ax, wagf[kk], accAG, 0, 0, 0);
            accBP = __builtin_amdgcn_mfma_f32_16x16x32_f16(ax, wbpf[kk], accBP, 0, 0, 0);
            accBG = __builtin_amdgcn_mfma_f32_16x16x32_f16(ax, wbgf[kk], accBG, 0, 0, 0);
        }
        int lp = rt * 16 + g * 4;            // local position 0..127
        int pb = p0 + lp;
        unsigned short pka[4], pkb[4];
        #pragma unroll
        for (int r = 0; r < 4; ++r) {
            float mu = smu[lp + r];
            float rstd = srstd[lp + r];
            float vAP = rstd * (accAP[r] - mu * C1ap) + C2ap + bap;
            float vAG = rstd * (accAG[r] - mu * C1ag) + C2ag + bag;
            float vBP = rstd * (accBP[r] - mu * C1bp) + C2bp + bbp;
            float vBG = rstd * (accBG[r] - mu * C1bg) + C2bg + bbg;
            float m = mask[pb + r];
            pka[r] = f2h(m * sigmoidf_(vAG) * vAP);
            pkb[r] = f2h(m * sigmoidf_(vBG) * vBP);
        }
        uint2 sta, stb;
        sta.x = pka[0] | ((unsigned)pka[1] << 16);
        sta.y = pka[2] | ((unsigned)pka[3] << 16);
        stb.x = pkb[0] | ((unsigned)pkb[1] << 16);
        stb.y = pkb[2] | ((unsigned)pkb[3] << 16);
        *(uint2*)(aBlk + lp) = sta;
        *(uint2*)(bBlk + lp) = stb;
    }
}

// ---------------------------------------------------------------------------
// k2 (VALIDATED R7 core; A/B reads adapted to blocked layout):
//   x_t[h][i][k] = sum_j a[i,j,h] * b[k,j,h]
//   a/b layout: [pblk][h][ppos]; j-segment (kt*64..) of row (i0+row) lives at
//   pblk = (i0+row)*4 + (kt>>1), offset (kt&1)*64 + ch*8 (16B contiguous).
// ---------------------------------------------------------------------------
__global__ __launch_bounds__(256, 2)
void k2_tri(const unsigned short* __restrict__ a_t,
            const unsigned short* __restrict__ b_t,
            unsigned short* __restrict__ x_t) {
    __shared__ char sA[16384];   // [128][64] f16 linear
    __shared__ char sB[16384];
    const int t = threadIdx.x;
    const int lane = t & 63;
    const int w = t >> 6;
    const int wr = w >> 1, wc = w & 1;
    const int h = blockIdx.y;
    const int i0 = (blockIdx.x >> 2) * 128;
    const int k0 = (blockIdx.x & 3) * 128;
    const size_t hoff = (size_t)h * 128;

    f32x4_t zero = {0.f, 0.f, 0.f, 0.f};
    f32x4_t acc[4][4];
    #pragma unroll
    for (int m = 0; m < 4; ++m)
        #pragma unroll
        for (int n = 0; n < 4; ++n) acc[m][n] = zero;

    for (int kt = 0; kt < 8; ++kt) {
        const int kb = (kt >> 1), ko = (kt & 1) * 64;
        #pragma unroll
        for (int pass = 0; pass < 4; ++pass) {
            int ci = pass * 256 + t;
            int row = ci >> 3, ch = ci & 7;
            const unsigned short* gA = a_t +
                (size_t)((i0 + row) * 4 + kb) * 16384 + hoff + ko + ch * 8;
            const unsigned short* gB = b_t +
                (size_t)((k0 + row) * 4 + kb) * 16384 + hoff + ko + ch * 8;
            GLOAD_LDS16(gA, sA + w * 1024 + pass * 4096);
            GLOAD_LDS16(gB, sB + w * 1024 + pass * 4096);
        }
        __syncthreads();
        #pragma unroll
        for (int ks = 0; ks < 2; ++ks) {
            f16x8_t af[4], bf[4];
            #pragma unroll
            for (int m = 0; m < 4; ++m) {
                int ar = wr * 64 + m * 16 + (lane & 15);
                af[m] = *(const f16x8_t*)(sA + ar * 128 + ks * 64 + (lane >> 4) * 16);
            }
            #pragma unroll
            for (int n = 0; n < 4; ++n) {
                int br = wc * 64 + n * 16 + (lane & 15);
                bf[n] = *(const f16x8_t*)(sB + br * 128 + ks * 64 + (lane >> 4) * 16);
            }
            #pragma unroll
            for (int m = 0; m < 4; ++m)
                #pragma unroll
                for (int n = 0; n < 4; ++n)
                    acc[m][n] = __builtin_amdgcn_mfma_f32_16x16x32_f16(af[m], bf[n], acc[m][n], 0, 0, 0);
        }
        __syncthreads();
    }
    #pragma unroll
    for (int m = 0; m < 4; ++m) {
        int i = i0 + wr * 64 + m * 16 + (lane >> 4) * 4;
        #pragma unroll
        for (int n = 0; n < 4; ++n) {
            int k = k0 + wc * 64 + n * 16 + (lane & 15);
            #pragma unroll
            for (int r = 0; r < 4; ++r) {
                x_t[(size_t)h * NPOS + (size_t)(i + r) * 512 + k] = f2h(acc[m][n][r]);
            }
        }
    }
}

// ---------------------------------------------------------------------------
// k3d (VALIDATED R21/R22): double LN-FOLDED output stage.
//   out = ( rstdX*(accX - muX*C1z) + C2z + bz ) *
//         sigmoid( rstdZ*(accG - muZ*C1g) + C2g + bg )
// ---------------------------------------------------------------------------
__global__ __launch_bounds__(512, 2)
void k3d(const unsigned short* __restrict__ x_t,
         const unsigned short* __restrict__ z16,
         const unsigned* __restrict__ mustd,
         const unsigned short* __restrict__ wt, const float* __restrict__ cc,
         const float* __restrict__ b_z, const float* __restrict__ b_g,
         float* __restrict__ out)
{
    __shared__ char sX[128 * ZSTRIDE];   // [128 pos][128 h] f16, padded rows
    __shared__ float smuX[128], srstdX[128];
    __shared__ float smuZ[128], srstdZ[128];
    const int t = threadIdx.x, lane = t & 63, w = t >> 6;
    const int g = lane >> 4;             // k-subgroup 0..3
    const int c = w * 16 + (lane & 15);  // this wave's output column
    const int p0 = blockIdx.x * 128;

    // ---- weight fragments (folded planes) ----
    f16x8_t wzf[4], wgf[4];
    #pragma unroll
    for (int kk = 0; kk < 4; ++kk) {
        int off = c * 128 + kk * 32 + g * 8;
        wzf[kk] = *(const f16x8_t*)(wt + 4 * 16384 + off);
        wgf[kk] = *(const f16x8_t*)(wt + 5 * 16384 + off);
    }
    const float bzv = b_z[c], bgv = b_g[c];
    const float C1z = cc[4 * 256 + c], C2z = cc[4 * 256 + 128 + c];
    const float C1g = cc[5 * 256 + c], C2g = cc[5 * 256 + 128 + c];

    // ---- z stats for this block's 128 rows ----
    if (t < 128) {
        unsigned v = mustd[p0 + t];
        smuZ[t] = h2f((unsigned short)(v & 0xffffu));
        srstdZ[t] = h2f((unsigned short)(v >> 16));
    }

    // ---- stage x transposed: lane = h-pair, wave = 16-p segment ----
    {
        const int hp = lane;
        const int ps = w * 16;
        const unsigned short* x0 = x_t + (size_t)(2 * hp) * NPOS + p0 + ps;
        const unsigned short* x1 = x_t + (size_t)(2 * hp + 1) * NPOS + p0 + ps;
        uint4 a0 = *(const uint4*)(x0);
        uint4 a1 = *(const uint4*)(x0 + 8);
        uint4 b0 = *(const uint4*)(x1);
        uint4 b1 = *(const uint4*)(x1 + 8);
        unsigned aw[8] = {a0.x, a0.y, a0.z, a0.w, a1.x, a1.y, a1.z, a1.w};
        unsigned bw[8] = {b0.x, b0.y, b0.z, b0.w, b1.x, b1.y, b1.z, b1.w};
        #pragma unroll
        for (int e = 0; e < 8; ++e) {
            int p = ps + 2 * e;
            *(unsigned*)(sX + p * ZSTRIDE + hp * 4) =
                (aw[e] & 0xffffu) | ((bw[e] & 0xffffu) << 16);
            *(unsigned*)(sX + (p + 1) * ZSTRIDE + hp * 4) =
                (aw[e] >> 16) | ((bw[e] >> 16) << 16);
        }
    }
    __syncthreads();
    // ---- x LN stats only (4 threads per position) ----
    {
        int pos = t >> 2, q = t & 3;
        float s = 0.f, s2 = 0.f;
        #pragma unroll
        for (int e = 0; e < 8; ++e) {
            uint2 vv = *(const uint2*)(sX + pos * ZSTRIDE + (q * 32 + e * 4) * 2);
            float v0 = h2f((unsigned short)(vv.x & 0xffffu));
            float v1 = h2f((unsigned short)(vv.x >> 16));
            float v2 = h2f((unsigned short)(vv.y & 0xffffu));
            float v3 = h2f((unsigned short)(vv.y >> 16));
            s  += v0 + v1 + v2 + v3;
            s2 += v0 * v0 + v1 * v1 + v2 * v2 + v3 * v3;
        }
        s  += __shfl_xor(s, 1);  s  += __shfl_xor(s, 2);
        s2 += __shfl_xor(s2, 1); s2 += __shfl_xor(s2, 2);
        float mu = s * (1.0f / 128.0f);
        float var = s2 * (1.0f / 128.0f) - mu * mu;
        if (q == 0) {
            smuX[pos] = mu;
            srstdX[pos] = rsqrtf(var + EPS_LN);
        }
    }
    __syncthreads();
    // ---- MFMA row tiles ----
    f32x4_t zero = {0.f, 0.f, 0.f, 0.f};
    for (int rt = 0; rt < 8; ++rt) {
        f32x4_t accX = zero, accG = zero;
        #pragma unroll
        for (int kk = 0; kk < 4; ++kk) {
            int row = rt * 16 + (lane & 15);
            f16x8_t ax = *(const f16x8_t*)(sX + row * ZSTRIDE + kk * 64 + g * 16);
            f16x8_t az = *(const f16x8_t*)(z16 + (size_t)(p0 + row) * 128 + kk * 32 + g * 8);
            accX = __builtin_amdgcn_mfma_f32_16x16x32_f16(ax, wzf[kk], accX, 0, 0, 0);
            accG = __builtin_amdgcn_mfma_f32_16x16x32_f16(az, wgf[kk], accG, 0, 0, 0);
        }
        int lr0 = rt * 16 + g * 4;
        #pragma unroll
        for (int r = 0; r < 4; ++r) {
            int lr = lr0 + r;
            float oz = srstdX[lr] * (accX[r] - smuX[lr] * C1z) + C2z + bzv;
            float lg = srstdZ[lr] * (accG[r] - smuZ[lr] * C1g) + C2g + bgv;
            out[(size_t)(p0 + lr) * 128 + c] = oz * sigmoidf_(lg);
        }
    }
}

extern "C" void kernel_launch(void* const* d_in, const int* in_sizes, int n_in,
                              void* d_out, int out_size, void* d_ws, size_t ws_size,
                              hipStream_t stream) {
    const float* z        = (const float*)d_in[0];
    const float* mask     = (const float*)d_in[1];
    const float* ln_in_g  = (const float*)d_in[2];
    const float* ln_in_b  = (const float*)d_in[3];
    const float* w_ap     = (const float*)d_in[4];
    const float* b_ap     = (const float*)d_in[5];
    const float* w_ag     = (const float*)d_in[6];
    const float* b_ag     = (const float*)d_in[7];
    const float* w_bp     = (const float*)d_in[8];
    const float* b_bp     = (const float*)d_in[9];
    const float* w_bg     = (const float*)d_in[10];
    const float* b_bg     = (const float*)d_in[11];
    const float* w_g      = (const float*)d_in[12];
    const float* b_g      = (const float*)d_in[13];
    const float* ln_out_g = (const float*)d_in[14];
    const float* ln_out_b = (const float*)d_in[15];
    const float* w_z      = (const float*)d_in[16];
    const float* b_z      = (const float*)d_in[17];
    float* out = (float*)d_out;

    char* ws = (char*)d_ws;
    const size_t MB64 = (size_t)NPOS * 128 * 2;   // 64 MB per f16 plane-set
    unsigned short* wt   = (unsigned short*)(ws);                 // 192 KB
    float*          cc   = (float*)(ws + 786432);                 // 6 KB
    unsigned*      mustd = (unsigned*)(ws + (1 << 20));           // 1 MB
    unsigned short* a_t  = (unsigned short*)(ws + (2 << 20));
    unsigned short* b_t  = (unsigned short*)(ws + (2 << 20) + MB64);
    unsigned short* x_t  = (unsigned short*)(ws + (2 << 20) + 2 * MB64);
    unsigned short* z16  = (unsigned short*)(ws + (2 << 20) + 3 * MB64); // 258 MB

    k_prep6<<<6, 256, 0, stream>>>(w_ap, w_ag, w_bp, w_bg, w_z, w_g,
                                   ln_in_g, ln_out_g, wt);
    k_const<<<6, 128, 0, stream>>>(w_ap, w_ag, w_bp, w_bg, w_z, w_g,
                                   ln_in_g, ln_in_b, ln_out_g, ln_out_b, cc);
    k1g<<<2048, 512, 0, stream>>>(z, mask, wt, cc,
                                  b_ap, b_ag, b_bp, b_bg,
                                  a_t, b_t, z16, mustd);
    k2_tri<<<dim3(16, 128), 256, 0, stream>>>(a_t, b_t, x_t);
    k3d<<<2048, 512, 0, stream>>>(x_t, z16, mustd, wt, cc, b_z, b_g, out);
}

// Round 25
// 341.243 us; speedup vs baseline: 1.0886x; 1.0074x over previous
//
#include <hip/hip_runtime.h>
#include <stdint.h>

#define NPOS 262144       // 512*512
#define EPS_LN 1e-5f
#define ZSTRIDE 272       // 128 f16 + 16B pad (breaks power-of-2 bank stride)

typedef _Float16 f16x8_t __attribute__((ext_vector_type(8)));
typedef float f32x4_t __attribute__((ext_vector_type(4)));

static __device__ __forceinline__ unsigned short f2h(float f) {
    union { _Float16 h; unsigned short u; } v;
    v.h = (_Float16)f;
    return v.u;
}
static __device__ __forceinline__ float h2f(unsigned short u) {
    union { unsigned short u; _Float16 h; } v;
    v.u = u;
    return (float)v.h;
}
static __device__ __forceinline__ float sigmoidf_(float x) {
    return 1.0f / (1.0f + __expf(-x));
}

#define GLOAD_LDS16(gp, lp) __builtin_amdgcn_global_load_lds( \
    (const __attribute__((address_space(1))) void*)(gp), \
    (__attribute__((address_space(3))) void*)(lp), 16, 0, 0)

// ---------------------------------------------------------------------------
// k_prep6: transpose+cast+FOLD 6 weight matrices -> f16 h-major planes.
// plane order: 0:ap 1:ag 2:bp 3:bg 4:z 5:g.
// Planes 0-3,5 folded with ln_in_g; plane 4 folded with ln_out_g.
// ---------------------------------------------------------------------------
__global__ __launch_bounds__(256)
void k_prep6(const float* w0, const float* w1, const float* w2,
             const float* w3, const float* w4, const float* w5,
             const float* lng, const float* lnog, unsigned short* wt) {
    const float* srcs[6] = {w0, w1, w2, w3, w4, w5};
    const float* src = srcs[blockIdx.x];
    const float* fold = (blockIdx.x == 4) ? lnog : lng;
    unsigned short* dst = wt + blockIdx.x * 16384;
    for (int rep = 0; rep < 64; ++rep) {
        int idx = rep * 256 + threadIdx.x;   // 0..16383
        int h = idx >> 7, k = idx & 127;
        dst[idx] = f2h(src[k * 128 + h] * fold[k]);
    }
}

// ---------------------------------------------------------------------------
// k_const: per matrix: C1[c]=sum_k gv[k]*W[k][c], C2[c]=sum_k bv[k]*W[k][c]
// cc layout: [6][2][128]
// ---------------------------------------------------------------------------
__global__ __launch_bounds__(128)
void k_const(const float* wap, const float* wag, const float* wbp,
             const float* wbg, const float* wz, const float* wg,
             const float* lng, const float* lnb,
             const float* lnog, const float* lnob, float* cc) {
    const float* Ws[6] = {wap, wag, wbp, wbg, wz, wg};
    const float* W = Ws[blockIdx.x];
    const float* gv = (blockIdx.x == 4) ? lnog : lng;
    const float* bv = (blockIdx.x == 4) ? lnob : lnb;
    int c = threadIdx.x;
    float s1 = 0.f, s2 = 0.f;
    for (int k = 0; k < 128; ++k) {
        float wv = W[k * 128 + c];
        s1 += gv[k] * wv;
        s2 += bv[k] * wv;
    }
    cc[blockIdx.x * 256 + c] = s1;
    cc[blockIdx.x * 256 + 128 + c] = s2;
}

// ---------------------------------------------------------------------------
// k1g (VALIDATED R24): LN-folded a/b projections, BLOCKED output layout
//   a_t/b_t: [pblk=p>>7][h][ppos=p&127] f16.
// Stages own 128 rows of z f32->f16 (LDS + z16 plane + stats), then MFMA.
// ---------------------------------------------------------------------------
__global__ __launch_bounds__(512, 2)
void k1g(const float* __restrict__ z, const float* __restrict__ mask,
         const unsigned short* __restrict__ wt, const float* __restrict__ cc,
         const float* __restrict__ b_ap, const float* __restrict__ b_ag,
         const float* __restrict__ b_bp, const float* __restrict__ b_bg,
         unsigned short* __restrict__ a_t, unsigned short* __restrict__ b_t,
         unsigned short* __restrict__ z16, unsigned* __restrict__ mustd)
{
    __shared__ char sZ[128 * ZSTRIDE];   // [128 pos][128 ch] raw f16 z
    __shared__ float smu[128];
    __shared__ float srstd[128];
    const int t = threadIdx.x;
    const int lane = t & 63;
    const int w = t >> 6;                // wave 0..7
    const int g = lane >> 4;             // k-subgroup 0..3
    const int l15 = lane & 15;
    const int h = w * 16 + l15;          // this wave's output column
    const int p0 = blockIdx.x * 128;

    // ---- stage raw z as f16 + stats (4 threads per position) ----
    {
        const int pos = t >> 2, q = t & 3;
        const float* zp = z + (size_t)(p0 + pos) * 128 + q * 32;
        float s = 0.f, s2 = 0.f;
        #pragma unroll
        for (int e = 0; e < 8; ++e) {
            float4 v = *(const float4*)(zp + e * 4);
            s += v.x + v.y + v.z + v.w;
            s2 += v.x * v.x + v.y * v.y + v.z * v.z + v.w * v.w;
            uint2 st;
            st.x = f2h(v.x) | ((unsigned)f2h(v.y) << 16);
            st.y = f2h(v.z) | ((unsigned)f2h(v.w) << 16);
            *(uint2*)(sZ + pos * ZSTRIDE + (q * 32 + e * 4) * 2) = st;
            *(uint2*)(z16 + (size_t)(p0 + pos) * 128 + q * 32 + e * 4) = st;
        }
        s  += __shfl_xor(s, 1);  s  += __shfl_xor(s, 2);
        s2 += __shfl_xor(s2, 1); s2 += __shfl_xor(s2, 2);
        float mu = s * (1.0f / 128.0f);
        float var = s2 * (1.0f / 128.0f) - mu * mu;
        float rstd = rsqrtf(var + EPS_LN);
        if (q == 0) {
            smu[pos] = mu;
            srstd[pos] = rstd;
            mustd[p0 + pos] = f2h(mu) | ((unsigned)f2h(rstd) << 16);
        }
    }

    // ---- weight B-fragments (folded planes) + constants ----
    f16x8_t wapf[4], wagf[4], wbpf[4], wbgf[4];
    #pragma unroll
    for (int kk = 0; kk < 4; ++kk) {
        int off = h * 128 + kk * 32 + g * 8;
        wapf[kk] = *(const f16x8_t*)(wt + 0 * 16384 + off);
        wagf[kk] = *(const f16x8_t*)(wt + 1 * 16384 + off);
        wbpf[kk] = *(const f16x8_t*)(wt + 2 * 16384 + off);
        wbgf[kk] = *(const f16x8_t*)(wt + 3 * 16384 + off);
    }
    const float C1ap = cc[0 * 256 + h], C2ap = cc[0 * 256 + 128 + h];
    const float C1ag = cc[1 * 256 + h], C2ag = cc[1 * 256 + 128 + h];
    const float C1bp = cc[2 * 256 + h], C2bp = cc[2 * 256 + 128 + h];
    const float C1bg = cc[3 * 256 + h], C2bg = cc[3 * 256 + 128 + h];
    const float bap = b_ap[h], bag = b_ag[h];
    const float bbp = b_bp[h], bbg = b_bg[h];
    __syncthreads();

    // ---- MFMA row tiles + blocked-layout stores ----
    unsigned short* aBlk = a_t + (size_t)blockIdx.x * 16384 + h * 128;
    unsigned short* bBlk = b_t + (size_t)blockIdx.x * 16384 + h * 128;
    f32x4_t zero = {0.f, 0.f, 0.f, 0.f};
    for (int rt = 0; rt < 8; ++rt) {
        f32x4_t accAP = zero, accAG = zero, accBP = zero, accBG = zero;
        #pragma unroll
        for (int kk = 0; kk < 4; ++kk) {
            f16x8_t ax = *(const f16x8_t*)(sZ + (rt * 16 + l15) * ZSTRIDE + kk * 64 + g * 16);
            accAP = __builtin_amdgcn_mfma_f32_16x16x32_f16(ax, wapf[kk], accAP, 0, 0, 0);
            accAG = __builtin_amdgcn_mfma_f32_16x16x32_f16(ax, wagf[kk], accAG, 0, 0, 0);
            accBP = __builtin_amdgcn_mfma_f32_16x16x32_f16(ax, wbpf[kk], accBP, 0, 0, 0);
            accBG = __builtin_amdgcn_mfma_f32_16x16x32_f16(ax, wbgf[kk], accBG, 0, 0, 0);
        }
        int lp = rt * 16 + g * 4;            // local position 0..127
        int pb = p0 + lp;
        unsigned short pka[4], pkb[4];
        #pragma unroll
        for (int r = 0; r < 4; ++r) {
            float mu = smu[lp + r];
            float rstd = srstd[lp + r];
            float vAP = rstd * (accAP[r] - mu * C1ap) + C2ap + bap;
            float vAG = rstd * (accAG[r] - mu * C1ag) + C2ag + bag;
            float vBP = rstd * (accBP[r] - mu * C1bp) + C2bp + bbp;
            float vBG = rstd * (accBG[r] - mu * C1bg) + C2bg + bbg;
            float m = mask[pb + r];
            pka[r] = f2h(m * sigmoidf_(vAG) * vAP);
            pkb[r] = f2h(m * sigmoidf_(vBG) * vBP);
        }
        uint2 sta, stb;
        sta.x = pka[0] | ((unsigned)pka[1] << 16);
        sta.y = pka[2] | ((unsigned)pka[3] << 16);
        stb.x = pkb[0] | ((unsigned)pkb[1] << 16);
        stb.y = pkb[2] | ((unsigned)pkb[3] << 16);
        *(uint2*)(aBlk + lp) = sta;
        *(uint2*)(bBlk + lp) = stb;
    }
}

// ---------------------------------------------------------------------------
// k2: triangle GEMM, blocked a/b inputs AND blocked x output.
//   x[pblk][h][ppos] with p = i*512 + k:
//   output element (i, k, h) -> pblk = i*4 + (k0>>7), ppos = k - k0.
//   (k0 multiple of 128, tile covers k0..k0+127.)
// ---------------------------------------------------------------------------
__global__ __launch_bounds__(256, 2)
void k2_tri(const unsigned short* __restrict__ a_t,
            const unsigned short* __restrict__ b_t,
            unsigned short* __restrict__ x_t) {
    __shared__ char sA[16384];   // [128][64] f16 linear
    __shared__ char sB[16384];
    const int t = threadIdx.x;
    const int lane = t & 63;
    const int w = t >> 6;
    const int wr = w >> 1, wc = w & 1;
    const int h = blockIdx.y;
    const int i0 = (blockIdx.x >> 2) * 128;
    const int k0 = (blockIdx.x & 3) * 128;
    const int kb4 = (blockIdx.x & 3);    // k0 >> 7
    const size_t hoff = (size_t)h * 128;

    f32x4_t zero = {0.f, 0.f, 0.f, 0.f};
    f32x4_t acc[4][4];
    #pragma unroll
    for (int m = 0; m < 4; ++m)
        #pragma unroll
        for (int n = 0; n < 4; ++n) acc[m][n] = zero;

    for (int kt = 0; kt < 8; ++kt) {
        const int kb = (kt >> 1), ko = (kt & 1) * 64;
        #pragma unroll
        for (int pass = 0; pass < 4; ++pass) {
            int ci = pass * 256 + t;
            int row = ci >> 3, ch = ci & 7;
            const unsigned short* gA = a_t +
                (size_t)((i0 + row) * 4 + kb) * 16384 + hoff + ko + ch * 8;
            const unsigned short* gB = b_t +
                (size_t)((k0 + row) * 4 + kb) * 16384 + hoff + ko + ch * 8;
            GLOAD_LDS16(gA, sA + w * 1024 + pass * 4096);
            GLOAD_LDS16(gB, sB + w * 1024 + pass * 4096);
        }
        __syncthreads();
        #pragma unroll
        for (int ks = 0; ks < 2; ++ks) {
            f16x8_t af[4], bf[4];
            #pragma unroll
            for (int m = 0; m < 4; ++m) {
                int ar = wr * 64 + m * 16 + (lane & 15);
                af[m] = *(const f16x8_t*)(sA + ar * 128 + ks * 64 + (lane >> 4) * 16);
            }
            #pragma unroll
            for (int n = 0; n < 4; ++n) {
                int br = wc * 64 + n * 16 + (lane & 15);
                bf[n] = *(const f16x8_t*)(sB + br * 128 + ks * 64 + (lane >> 4) * 16);
            }
            #pragma unroll
            for (int m = 0; m < 4; ++m)
                #pragma unroll
                for (int n = 0; n < 4; ++n)
                    acc[m][n] = __builtin_amdgcn_mfma_f32_16x16x32_f16(af[m], bf[n], acc[m][n], 0, 0, 0);
        }
        __syncthreads();
    }
    // blocked-layout C-write: 16 lanes store 32B contiguous per (m,n,r)
    #pragma unroll
    for (int m = 0; m < 4; ++m) {
        int ibase = i0 + wr * 64 + m * 16 + (lane >> 4) * 4;
        #pragma unroll
        for (int n = 0; n < 4; ++n) {
            int ppos = wc * 64 + n * 16 + (lane & 15);
            #pragma unroll
            for (int r = 0; r < 4; ++r) {
                x_t[(size_t)((ibase + r) * 4 + kb4) * 16384 + hoff + ppos] =
                    f2h(acc[m][n][r]);
            }
        }
    }
}

// ---------------------------------------------------------------------------
// k3d: double LN-FOLDED output stage; x input in BLOCKED layout.
//   Block's entire x-tile = x_t + blockIdx.x*16384 (32 KB contiguous).
// ---------------------------------------------------------------------------
__global__ __launch_bounds__(512, 2)
void k3d(const unsigned short* __restrict__ x_t,
         const unsigned short* __restrict__ z16,
         const unsigned* __restrict__ mustd,
         const unsigned short* __restrict__ wt, const float* __restrict__ cc,
         const float* __restrict__ b_z, const float* __restrict__ b_g,
         float* __restrict__ out)
{
    __shared__ char sX[128 * ZSTRIDE];   // [128 pos][128 h] f16, padded rows
    __shared__ float smuX[128], srstdX[128];
    __shared__ float smuZ[128], srstdZ[128];
    const int t = threadIdx.x, lane = t & 63, w = t >> 6;
    const int g = lane >> 4;             // k-subgroup 0..3
    const int c = w * 16 + (lane & 15);  // this wave's output column
    const int p0 = blockIdx.x * 128;

    // ---- weight fragments (folded planes) ----
    f16x8_t wzf[4], wgf[4];
    #pragma unroll
    for (int kk = 0; kk < 4; ++kk) {
        int off = c * 128 + kk * 32 + g * 8;
        wzf[kk] = *(const f16x8_t*)(wt + 4 * 16384 + off);
        wgf[kk] = *(const f16x8_t*)(wt + 5 * 16384 + off);
    }
    const float bzv = b_z[c], bgv = b_g[c];
    const float C1z = cc[4 * 256 + c], C2z = cc[4 * 256 + 128 + c];
    const float C1g = cc[5 * 256 + c], C2g = cc[5 * 256 + 128 + c];

    // ---- z stats for this block's 128 rows ----
    if (t < 128) {
        unsigned v = mustd[p0 + t];
        smuZ[t] = h2f((unsigned short)(v & 0xffffu));
        srstdZ[t] = h2f((unsigned short)(v >> 16));
    }

    // ---- stage x transposed from CONTIGUOUS 32KB block ----
    {
        const unsigned short* xb = x_t + (size_t)blockIdx.x * 16384;
        const int hp = lane;
        const int ps = w * 16;
        const unsigned short* x0 = xb + (2 * hp) * 128 + ps;
        const unsigned short* x1 = xb + (2 * hp + 1) * 128 + ps;
        uint4 a0 = *(const uint4*)(x0);
        uint4 a1 = *(const uint4*)(x0 + 8);
        uint4 b0 = *(const uint4*)(x1);
        uint4 b1 = *(const uint4*)(x1 + 8);
        unsigned aw[8] = {a0.x, a0.y, a0.z, a0.w, a1.x, a1.y, a1.z, a1.w};
        unsigned bw[8] = {b0.x, b0.y, b0.z, b0.w, b1.x, b1.y, b1.z, b1.w};
        #pragma unroll
        for (int e = 0; e < 8; ++e) {
            int p = ps + 2 * e;
            *(unsigned*)(sX + p * ZSTRIDE + hp * 4) =
                (aw[e] & 0xffffu) | ((bw[e] & 0xffffu) << 16);
            *(unsigned*)(sX + (p + 1) * ZSTRIDE + hp * 4) =
                (aw[e] >> 16) | ((bw[e] >> 16) << 16);
        }
    }
    __syncthreads();
    // ---- x LN stats only (4 threads per position) ----
    {
        int pos = t >> 2, q = t & 3;
        float s = 0.f, s2 = 0.f;
        #pragma unroll
        for (int e = 0; e < 8; ++e) {
            uint2 vv = *(const uint2*)(sX + pos * ZSTRIDE + (q * 32 + e * 4) * 2);
            float v0 = h2f((unsigned short)(vv.x & 0xffffu));
            float v1 = h2f((unsigned short)(vv.x >> 16));
            float v2 = h2f((unsigned short)(vv.y & 0xffffu));
            float v3 = h2f((unsigned short)(vv.y >> 16));
            s  += v0 + v1 + v2 + v3;
            s2 += v0 * v0 + v1 * v1 + v2 * v2 + v3 * v3;
        }
        s  += __shfl_xor(s, 1);  s  += __shfl_xor(s, 2);
        s2 += __shfl_xor(s2, 1); s2 += __shfl_xor(s2, 2);
        float mu = s * (1.0f / 128.0f);
        float var = s2 * (1.0f / 128.0f) - mu * mu;
        if (q == 0) {
            smuX[pos] = mu;
            srstdX[pos] = rsqrtf(var + EPS_LN);
        }
    }
    __syncthreads();
    // ---- MFMA row tiles ----
    f32x4_t zero = {0.f, 0.f, 0.f, 0.f};
    for (int rt = 0; rt < 8; ++rt) {
        f32x4_t accX = zero, accG = zero;
        #pragma unroll
        for (int kk = 0; kk < 4; ++kk) {
            int row = rt * 16 + (lane & 15);
            f16x8_t ax = *(const f16x8_t*)(sX + row * ZSTRIDE + kk * 64 + g * 16);
            f16x8_t az = *(const f16x8_t*)(z16 + (size_t)(p0 + row) * 128 + kk * 32 + g * 8);
            accX = __builtin_amdgcn_mfma_f32_16x16x32_f16(ax, wzf[kk], accX, 0, 0, 0);
            accG = __builtin_amdgcn_mfma_f32_16x16x32_f16(az, wgf[kk], accG, 0, 0, 0);
        }
        int lr0 = rt * 16 + g * 4;
        #pragma unroll
        for (int r = 0; r < 4; ++r) {
            int lr = lr0 + r;
            float oz = srstdX[lr] * (accX[r] - smuX[lr] * C1z) + C2z + bzv;
            float lg = srstdZ[lr] * (accG[r] - smuZ[lr] * C1g) + C2g + bgv;
            out[(size_t)(p0 + lr) * 128 + c] = oz * sigmoidf_(lg);
        }
    }
}

extern "C" void kernel_launch(void* const* d_in, const int* in_sizes, int n_in,
                              void* d_out, int out_size, void* d_ws, size_t ws_size,
                              hipStream_t stream) {
    const float* z        = (const float*)d_in[0];
    const float* mask     = (const float*)d_in[1];
    const float* ln_in_g  = (const float*)d_in[2];
    const float* ln_in_b  = (const float*)d_in[3];
    const float* w_ap     = (const float*)d_in[4];
    const float* b_ap     = (const float*)d_in[5];
    const float* w_ag     = (const float*)d_in[6];
    const float* b_ag     = (const float*)d_in[7];
    const float* w_bp     = (const float*)d_in[8];
    const float* b_bp     = (const float*)d_in[9];
    const float* w_bg     = (const float*)d_in[10];
    const float* b_bg     = (const float*)d_in[11];
    const float* w_g      = (const float*)d_in[12];
    const float* b_g      = (const float*)d_in[13];
    const float* ln_out_g = (const float*)d_in[14];
    const float* ln_out_b = (const float*)d_in[15];
    const float* w_z      = (const float*)d_in[16];
    const float* b_z      = (const float*)d_in[17];
    float* out = (float*)d_out;

    char* ws = (char*)d_ws;
    const size_t MB64 = (size_t)NPOS * 128 * 2;   // 64 MB per f16 plane-set
    unsigned short* wt   = (unsigned short*)(ws);                 // 192 KB
    float*          cc   = (float*)(ws + 786432);                 // 6 KB
    unsigned*      mustd = (unsigned*)(ws + (1 << 20));           // 1 MB
    unsigned short* a_t  = (unsigned short*)(ws + (2 << 20));
    unsigned short* b_t  = (unsigned short*)(ws + (2 << 20) + MB64);
    unsigned short* x_t  = (unsigned short*)(ws + (2 << 20) + 2 * MB64);
    unsigned short* z16  = (unsigned short*)(ws + (2 << 20) + 3 * MB64); // 258 MB

    k_prep6<<<6, 256, 0, stream>>>(w_ap, w_ag, w_bp, w_bg, w_z, w_g,
                                   ln_in_g, ln_out_g, wt);
    k_const<<<6, 128, 0, stream>>>(w_ap, w_ag, w_bp, w_bg, w_z, w_g,
                                   ln_in_g, ln_in_b, ln_out_g, ln_out_b, cc);
    k1g<<<2048, 512, 0, stream>>>(z, mask, wt, cc,
                                  b_ap, b_ag, b_bp, b_bg,
                                  a_t, b_t, z16, mustd);
    k2_tri<<<dim3(16, 128), 256, 0, stream>>>(a_t, b_t, x_t);
    k3d<<<2048, 512, 0, stream>>>(x_t, z16, mustd, wt, cc, b_z, b_g, out);
}

// Round 26
// 336.179 us; speedup vs baseline: 1.1050x; 1.0151x over previous
//
#include <hip/hip_runtime.h>
#include <stdint.h>

#define NPOS 262144       // 512*512
#define EPS_LN 1e-5f
#define ZSTRIDE 272       // 128 f16 + 16B pad (breaks power-of-2 bank stride)

typedef _Float16 f16x8_t __attribute__((ext_vector_type(8)));
typedef float f32x4_t __attribute__((ext_vector_type(4)));

static __device__ __forceinline__ unsigned short f2h(float f) {
    union { _Float16 h; unsigned short u; } v;
    v.h = (_Float16)f;
    return v.u;
}
static __device__ __forceinline__ float h2f(unsigned short u) {
    union { unsigned short u; _Float16 h; } v;
    v.u = u;
    return (float)v.h;
}
static __device__ __forceinline__ float sigmoidf_(float x) {
    return 1.0f / (1.0f + __expf(-x));
}

#define GLOAD_LDS16(gp, lp) __builtin_amdgcn_global_load_lds( \
    (const __attribute__((address_space(1))) void*)(gp), \
    (__attribute__((address_space(3))) void*)(lp), 16, 0, 0)

// ---------------------------------------------------------------------------
// k_prep6: transpose+cast+FOLD 6 weight matrices -> f16 h-major planes.
// plane order: 0:ap 1:ag 2:bp 3:bg 4:z 5:g.
// Planes 0-3,5 folded with ln_in_g; plane 4 folded with ln_out_g.
// ---------------------------------------------------------------------------
__global__ __launch_bounds__(256)
void k_prep6(const float* w0, const float* w1, const float* w2,
             const float* w3, const float* w4, const float* w5,
             const float* lng, const float* lnog, unsigned short* wt) {
    const float* srcs[6] = {w0, w1, w2, w3, w4, w5};
    const float* src = srcs[blockIdx.x];
    const float* fold = (blockIdx.x == 4) ? lnog : lng;
    unsigned short* dst = wt + blockIdx.x * 16384;
    for (int rep = 0; rep < 64; ++rep) {
        int idx = rep * 256 + threadIdx.x;   // 0..16383
        int h = idx >> 7, k = idx & 127;
        dst[idx] = f2h(src[k * 128 + h] * fold[k]);
    }
}

// ---------------------------------------------------------------------------
// k_const: per matrix: C1[c]=sum_k gv[k]*W[k][c], C2[c]=sum_k bv[k]*W[k][c]
// cc layout: [6][2][128]
// ---------------------------------------------------------------------------
__global__ __launch_bounds__(128)
void k_const(const float* wap, const float* wag, const float* wbp,
             const float* wbg, const float* wz, const float* wg,
             const float* lng, const float* lnb,
             const float* lnog, const float* lnob, float* cc) {
    const float* Ws[6] = {wap, wag, wbp, wbg, wz, wg};
    const float* W = Ws[blockIdx.x];
    const float* gv = (blockIdx.x == 4) ? lnog : lng;
    const float* bv = (blockIdx.x == 4) ? lnob : lnb;
    int c = threadIdx.x;
    float s1 = 0.f, s2 = 0.f;
    for (int k = 0; k < 128; ++k) {
        float wv = W[k * 128 + c];
        s1 += gv[k] * wv;
        s2 += bv[k] * wv;
    }
    cc[blockIdx.x * 256 + c] = s1;
    cc[blockIdx.x * 256 + 128 + c] = s2;
}

// ---------------------------------------------------------------------------
// k1h: LN-folded a/b projections, SMALL-BLOCK two-pass variant.
// 256 threads (4 waves), 64 positions/block, grid 4096 -> 5+ blocks/CU so
// staging/MFMA/store phases of DIFFERENT blocks overlap on each CU
// (R25 diagnosis: one barrier-coupled 512-thr block/CU => phase serialization,
//  2.0 TB/s effective on 316 MB => 162 us).
// Two h-passes per block (hp=0: h<64, hp=1: h>=64), weights reloaded per pass.
// Blocked a/b layout [pblk=p>>7][h][ppos=p&127]: pblk = blockIdx.x>>1,
// ppos = (blockIdx.x&1)*64 + lp.
// ---------------------------------------------------------------------------
__global__ __launch_bounds__(256)
void k1h(const float* __restrict__ z, const float* __restrict__ mask,
         const unsigned short* __restrict__ wt, const float* __restrict__ cc,
         const float* __restrict__ b_ap, const float* __restrict__ b_ag,
         const float* __restrict__ b_bp, const float* __restrict__ b_bg,
         unsigned short* __restrict__ a_t, unsigned short* __restrict__ b_t,
         unsigned short* __restrict__ z16, unsigned* __restrict__ mustd)
{
    __shared__ char sZ[64 * ZSTRIDE];    // [64 pos][128 ch] raw f16 z
    __shared__ float smu[64];
    __shared__ float srstd[64];
    const int t = threadIdx.x;
    const int lane = t & 63;
    const int w = t >> 6;                // wave 0..3
    const int g = lane >> 4;             // k-subgroup 0..3
    const int l15 = lane & 15;
    const int p0 = blockIdx.x * 64;

    // ---- stage raw z as f16 + stats (4 threads per position) ----
    {
        const int pos = t >> 2, q = t & 3;     // pos 0..63
        const float* zp = z + (size_t)(p0 + pos) * 128 + q * 32;
        float s = 0.f, s2 = 0.f;
        #pragma unroll
        for (int e = 0; e < 8; ++e) {
            float4 v = *(const float4*)(zp + e * 4);
            s += v.x + v.y + v.z + v.w;
            s2 += v.x * v.x + v.y * v.y + v.z * v.z + v.w * v.w;
            uint2 st;
            st.x = f2h(v.x) | ((unsigned)f2h(v.y) << 16);
            st.y = f2h(v.z) | ((unsigned)f2h(v.w) << 16);
            *(uint2*)(sZ + pos * ZSTRIDE + (q * 32 + e * 4) * 2) = st;
            *(uint2*)(z16 + (size_t)(p0 + pos) * 128 + q * 32 + e * 4) = st;
        }
        s  += __shfl_xor(s, 1);  s  += __shfl_xor(s, 2);
        s2 += __shfl_xor(s2, 1); s2 += __shfl_xor(s2, 2);
        float mu = s * (1.0f / 128.0f);
        float var = s2 * (1.0f / 128.0f) - mu * mu;
        float rstd = rsqrtf(var + EPS_LN);
        if (q == 0) {
            smu[pos] = mu;
            srstd[pos] = rstd;
            mustd[p0 + pos] = f2h(mu) | ((unsigned)f2h(rstd) << 16);
        }
    }
    __syncthreads();

    const size_t blkBase = (size_t)(blockIdx.x >> 1) * 16384;
    const int pq = (blockIdx.x & 1) * 64;     // ppos base for this half-pblk

    // ---- two h-passes: hp=0 -> h in [0,64), hp=1 -> h in [64,128) ----
    #pragma unroll 1
    for (int hp = 0; hp < 2; ++hp) {
        const int h = hp * 64 + w * 16 + l15;
        f16x8_t wapf[4], wagf[4], wbpf[4], wbgf[4];
        #pragma unroll
        for (int kk = 0; kk < 4; ++kk) {
            int off = h * 128 + kk * 32 + g * 8;
            wapf[kk] = *(const f16x8_t*)(wt + 0 * 16384 + off);
            wagf[kk] = *(const f16x8_t*)(wt + 1 * 16384 + off);
            wbpf[kk] = *(const f16x8_t*)(wt + 2 * 16384 + off);
            wbgf[kk] = *(const f16x8_t*)(wt + 3 * 16384 + off);
        }
        const float C1ap = cc[0 * 256 + h], C2ap = cc[0 * 256 + 128 + h];
        const float C1ag = cc[1 * 256 + h], C2ag = cc[1 * 256 + 128 + h];
        const float C1bp = cc[2 * 256 + h], C2bp = cc[2 * 256 + 128 + h];
        const float C1bg = cc[3 * 256 + h], C2bg = cc[3 * 256 + 128 + h];
        const float bap = b_ap[h], bag = b_ag[h];
        const float bbp = b_bp[h], bbg = b_bg[h];

        unsigned short* aBlk = a_t + blkBase + (size_t)h * 128 + pq;
        unsigned short* bBlk = b_t + blkBase + (size_t)h * 128 + pq;

        f32x4_t zero = {0.f, 0.f, 0.f, 0.f};
        for (int rt = 0; rt < 4; ++rt) {
            f32x4_t accAP = zero, accAG = zero, accBP = zero, accBG = zero;
            #pragma unroll
            for (int kk = 0; kk < 4; ++kk) {
                f16x8_t ax = *(const f16x8_t*)(sZ + (rt * 16 + l15) * ZSTRIDE + kk * 64 + g * 16);
                accAP = __builtin_amdgcn_mfma_f32_16x16x32_f16(ax, wapf[kk], accAP, 0, 0, 0);
                accAG = __builtin_amdgcn_mfma_f32_16x16x32_f16(ax, wagf[kk], accAG, 0, 0, 0);
                accBP = __builtin_amdgcn_mfma_f32_16x16x32_f16(ax, wbpf[kk], accBP, 0, 0, 0);
                accBG = __builtin_amdgcn_mfma_f32_16x16x32_f16(ax, wbgf[kk], accBG, 0, 0, 0);
            }
            int lp = rt * 16 + g * 4;            // local position 0..63
            int pb = p0 + lp;
            unsigned short pka[4], pkb[4];
            #pragma unroll
            for (int r = 0; r < 4; ++r) {
                float mu = smu[lp + r];
                float rstd = srstd[lp + r];
                float vAP = rstd * (accAP[r] - mu * C1ap) + C2ap + bap;
                float vAG = rstd * (accAG[r] - mu * C1ag) + C2ag + bag;
                float vBP = rstd * (accBP[r] - mu * C1bp) + C2bp + bbp;
                float vBG = rstd * (accBG[r] - mu * C1bg) + C2bg + bbg;
                float m = mask[pb + r];
                pka[r] = f2h(m * sigmoidf_(vAG) * vAP);
                pkb[r] = f2h(m * sigmoidf_(vBG) * vBP);
            }
            uint2 sta, stb;
            sta.x = pka[0] | ((unsigned)pka[1] << 16);
            sta.y = pka[2] | ((unsigned)pka[3] << 16);
            stb.x = pkb[0] | ((unsigned)pkb[1] << 16);
            stb.y = pkb[2] | ((unsigned)pkb[3] << 16);
            *(uint2*)(aBlk + lp) = sta;
            *(uint2*)(bBlk + lp) = stb;
        }
    }
}

// ---------------------------------------------------------------------------
// k2 (VALIDATED R25): triangle GEMM, blocked a/b inputs AND blocked x output.
// ---------------------------------------------------------------------------
__global__ __launch_bounds__(256, 2)
void k2_tri(const unsigned short* __restrict__ a_t,
            const unsigned short* __restrict__ b_t,
            unsigned short* __restrict__ x_t) {
    __shared__ char sA[16384];   // [128][64] f16 linear
    __shared__ char sB[16384];
    const int t = threadIdx.x;
    const int lane = t & 63;
    const int w = t >> 6;
    const int wr = w >> 1, wc = w & 1;
    const int h = blockIdx.y;
    const int i0 = (blockIdx.x >> 2) * 128;
    const int k0 = (blockIdx.x & 3) * 128;
    const int kb4 = (blockIdx.x & 3);    // k0 >> 7
    const size_t hoff = (size_t)h * 128;

    f32x4_t zero = {0.f, 0.f, 0.f, 0.f};
    f32x4_t acc[4][4];
    #pragma unroll
    for (int m = 0; m < 4; ++m)
        #pragma unroll
        for (int n = 0; n < 4; ++n) acc[m][n] = zero;

    for (int kt = 0; kt < 8; ++kt) {
        const int kb = (kt >> 1), ko = (kt & 1) * 64;
        #pragma unroll
        for (int pass = 0; pass < 4; ++pass) {
            int ci = pass * 256 + t;
            int row = ci >> 3, ch = ci & 7;
            const unsigned short* gA = a_t +
                (size_t)((i0 + row) * 4 + kb) * 16384 + hoff + ko + ch * 8;
            const unsigned short* gB = b_t +
                (size_t)((k0 + row) * 4 + kb) * 16384 + hoff + ko + ch * 8;
            GLOAD_LDS16(gA, sA + w * 1024 + pass * 4096);
            GLOAD_LDS16(gB, sB + w * 1024 + pass * 4096);
        }
        __syncthreads();
        #pragma unroll
        for (int ks = 0; ks < 2; ++ks) {
            f16x8_t af[4], bf[4];
            #pragma unroll
            for (int m = 0; m < 4; ++m) {
                int ar = wr * 64 + m * 16 + (lane & 15);
                af[m] = *(const f16x8_t*)(sA + ar * 128 + ks * 64 + (lane >> 4) * 16);
            }
            #pragma unroll
            for (int n = 0; n < 4; ++n) {
                int br = wc * 64 + n * 16 + (lane & 15);
                bf[n] = *(const f16x8_t*)(sB + br * 128 + ks * 64 + (lane >> 4) * 16);
            }
            #pragma unroll
            for (int m = 0; m < 4; ++m)
                #pragma unroll
                for (int n = 0; n < 4; ++n)
                    acc[m][n] = __builtin_amdgcn_mfma_f32_16x16x32_f16(af[m], bf[n], acc[m][n], 0, 0, 0);
        }
        __syncthreads();
    }
    // blocked-layout C-write: 16 lanes store 32B contiguous per (m,n,r)
    #pragma unroll
    for (int m = 0; m < 4; ++m) {
        int ibase = i0 + wr * 64 + m * 16 + (lane >> 4) * 4;
        #pragma unroll
        for (int n = 0; n < 4; ++n) {
            int ppos = wc * 64 + n * 16 + (lane & 15);
            #pragma unroll
            for (int r = 0; r < 4; ++r) {
                x_t[(size_t)((ibase + r) * 4 + kb4) * 16384 + hoff + ppos] =
                    f2h(acc[m][n][r]);
            }
        }
    }
}

// ---------------------------------------------------------------------------
// k3d (VALIDATED R25): double LN-FOLDED output stage; x in BLOCKED layout.
// ---------------------------------------------------------------------------
__global__ __launch_bounds__(512, 2)
void k3d(const unsigned short* __restrict__ x_t,
         const unsigned short* __restrict__ z16,
         const unsigned* __restrict__ mustd,
         const unsigned short* __restrict__ wt, const float* __restrict__ cc,
         const float* __restrict__ b_z, const float* __restrict__ b_g,
         float* __restrict__ out)
{
    __shared__ char sX[128 * ZSTRIDE];   // [128 pos][128 h] f16, padded rows
    __shared__ float smuX[128], srstdX[128];
    __shared__ float smuZ[128], srstdZ[128];
    const int t = threadIdx.x, lane = t & 63, w = t >> 6;
    const int g = lane >> 4;             // k-subgroup 0..3
    const int c = w * 16 + (lane & 15);  // this wave's output column
    const int p0 = blockIdx.x * 128;

    // ---- weight fragments (folded planes) ----
    f16x8_t wzf[4], wgf[4];
    #pragma unroll
    for (int kk = 0; kk < 4; ++kk) {
        int off = c * 128 + kk * 32 + g * 8;
        wzf[kk] = *(const f16x8_t*)(wt + 4 * 16384 + off);
        wgf[kk] = *(const f16x8_t*)(wt + 5 * 16384 + off);
    }
    const float bzv = b_z[c], bgv = b_g[c];
    const float C1z = cc[4 * 256 + c], C2z = cc[4 * 256 + 128 + c];
    const float C1g = cc[5 * 256 + c], C2g = cc[5 * 256 + 128 + c];

    // ---- z stats for this block's 128 rows ----
    if (t < 128) {
        unsigned v = mustd[p0 + t];
        smuZ[t] = h2f((unsigned short)(v & 0xffffu));
        srstdZ[t] = h2f((unsigned short)(v >> 16));
    }

    // ---- stage x transposed from CONTIGUOUS 32KB block ----
    {
        const unsigned short* xb = x_t + (size_t)blockIdx.x * 16384;
        const int hp = lane;
        const int ps = w * 16;
        const unsigned short* x0 = xb + (2 * hp) * 128 + ps;
        const unsigned short* x1 = xb + (2 * hp + 1) * 128 + ps;
        uint4 a0 = *(const uint4*)(x0);
        uint4 a1 = *(const uint4*)(x0 + 8);
        uint4 b0 = *(const uint4*)(x1);
        uint4 b1 = *(const uint4*)(x1 + 8);
        unsigned aw[8] = {a0.x, a0.y, a0.z, a0.w, a1.x, a1.y, a1.z, a1.w};
        unsigned bw[8] = {b0.x, b0.y, b0.z, b0.w, b1.x, b1.y, b1.z, b1.w};
        #pragma unroll
        for (int e = 0; e < 8; ++e) {
            int p = ps + 2 * e;
            *(unsigned*)(sX + p * ZSTRIDE + hp * 4) =
                (aw[e] & 0xffffu) | ((bw[e] & 0xffffu) << 16);
            *(unsigned*)(sX + (p + 1) * ZSTRIDE + hp * 4) =
                (aw[e] >> 16) | ((bw[e] >> 16) << 16);
        }
    }
    __syncthreads();
    // ---- x LN stats only (4 threads per position) ----
    {
        int pos = t >> 2, q = t & 3;
        float s = 0.f, s2 = 0.f;
        #pragma unroll
        for (int e = 0; e < 8; ++e) {
            uint2 vv = *(const uint2*)(sX + pos * ZSTRIDE + (q * 32 + e * 4) * 2);
            float v0 = h2f((unsigned short)(vv.x & 0xffffu));
            float v1 = h2f((unsigned short)(vv.x >> 16));
            float v2 = h2f((unsigned short)(vv.y & 0xffffu));
            float v3 = h2f((unsigned short)(vv.y >> 16));
            s  += v0 + v1 + v2 + v3;
            s2 += v0 * v0 + v1 * v1 + v2 * v2 + v3 * v3;
        }
        s  += __shfl_xor(s, 1);  s  += __shfl_xor(s, 2);
        s2 += __shfl_xor(s2, 1); s2 += __shfl_xor(s2, 2);
        float mu = s * (1.0f / 128.0f);
        float var = s2 * (1.0f / 128.0f) - mu * mu;
        if (q == 0) {
            smuX[pos] = mu;
            srstdX[pos] = rsqrtf(var + EPS_LN);
        }
    }
    __syncthreads();
    // ---- MFMA row tiles ----
    f32x4_t zero = {0.f, 0.f, 0.f, 0.f};
    for (int rt = 0; rt < 8; ++rt) {
        f32x4_t accX = zero, accG = zero;
        #pragma unroll
        for (int kk = 0; kk < 4; ++kk) {
            int row = rt * 16 + (lane & 15);
            f16x8_t ax = *(const f16x8_t*)(sX + row * ZSTRIDE + kk * 64 + g * 16);
            f16x8_t az = *(const f16x8_t*)(z16 + (size_t)(p0 + row) * 128 + kk * 32 + g * 8);
            accX = __builtin_amdgcn_mfma_f32_16x16x32_f16(ax, wzf[kk], accX, 0, 0, 0);
            accG = __builtin_amdgcn_mfma_f32_16x16x32_f16(az, wgf[kk], accG, 0, 0, 0);
        }
        int lr0 = rt * 16 + g * 4;
        #pragma unroll
        for (int r = 0; r < 4; ++r) {
            int lr = lr0 + r;
            float oz = srstdX[lr] * (accX[r] - smuX[lr] * C1z) + C2z + bzv;
            float lg = srstdZ[lr] * (accG[r] - smuZ[lr] * C1g) + C2g + bgv;
            out[(size_t)(p0 + lr) * 128 + c] = oz * sigmoidf_(lg);
        }
    }
}

extern "C" void kernel_launch(void* const* d_in, const int* in_sizes, int n_in,
                              void* d_out, int out_size, void* d_ws, size_t ws_size,
                              hipStream_t stream) {
    const float* z        = (const float*)d_in[0];
    const float* mask     = (const float*)d_in[1];
    const float* ln_in_g  = (const float*)d_in[2];
    const float* ln_in_b  = (const float*)d_in[3];
    const float* w_ap     = (const float*)d_in[4];
    const float* b_ap     = (const float*)d_in[5];
    const float* w_ag     = (const float*)d_in[6];
    const float* b_ag     = (const float*)d_in[7];
    const float* w_bp     = (const float*)d_in[8];
    const float* b_bp     = (const float*)d_in[9];
    const float* w_bg     = (const float*)d_in[10];
    const float* b_bg     = (const float*)d_in[11];
    const float* w_g      = (const float*)d_in[12];
    const float* b_g      = (const float*)d_in[13];
    const float* ln_out_g = (const float*)d_in[14];
    const float* ln_out_b = (const float*)d_in[15];
    const float* w_z      = (const float*)d_in[16];
    const float* b_z      = (const float*)d_in[17];
    float* out = (float*)d_out;

    char* ws = (char*)d_ws;
    const size_t MB64 = (size_t)NPOS * 128 * 2;   // 64 MB per f16 plane-set
    unsigned short* wt   = (unsigned short*)(ws);                 // 192 KB
    float*          cc   = (float*)(ws + 786432);                 // 6 KB
    unsigned*      mustd = (unsigned*)(ws + (1 << 20));           // 1 MB
    unsigned short* a_t  = (unsigned short*)(ws + (2 << 20));
    unsigned short* b_t  = (unsigned short*)(ws + (2 << 20) + MB64);
    unsigned short* x_t  = (unsigned short*)(ws + (2 << 20) + 2 * MB64);
    unsigned short* z16  = (unsigned short*)(ws + (2 << 20) + 3 * MB64); // 258 MB

    k_prep6<<<6, 256, 0, stream>>>(w_ap, w_ag, w_bp, w_bg, w_z, w_g,
                                   ln_in_g, ln_out_g, wt);
    k_const<<<6, 128, 0, stream>>>(w_ap, w_ag, w_bp, w_bg, w_z, w_g,
                                   ln_in_g, ln_in_b, ln_out_g, ln_out_b, cc);
    k1h<<<4096, 256, 0, stream>>>(z, mask, wt, cc,
                                  b_ap, b_ag, b_bp, b_bg,
                                  a_t, b_t, z16, mustd);
    k2_tri<<<dim3(16, 128), 256, 0, stream>>>(a_t, b_t, x_t);
    k3d<<<2048, 512, 0, stream>>>(x_t, z16, mustd, wt, cc, b_z, b_g, out);
}